// Round 6
// baseline (483.948 us; speedup 1.0000x reference)
//
#include <hip/hip_runtime.h>
#include <hip/hip_cooperative_groups.h>
#include <math.h>

namespace cg = cooperative_groups;

typedef float  f32x4  __attribute__((ext_vector_type(4)));
typedef short  bf16x8 __attribute__((ext_vector_type(8)));
typedef unsigned short u16;
typedef unsigned int   u32;
typedef unsigned short u16x4 __attribute__((ext_vector_type(4)));

constexpr int Tn = 43, Hd = 1024, Nb = 512;

__device__ __forceinline__ u16 f2bf(float f) {
    u32 u = __float_as_uint(f);
    u32 r = u + 0x7FFFu + ((u >> 16) & 1u);
    return (u16)(r >> 16);
}
__device__ __forceinline__ float bf2f(u16 h) {
    return __uint_as_float(((u32)h) << 16);
}

// ===========================================================================
// PREP kernel: all weight conversions + CLS embed + bias folds. Segmented.
//  [0,9216)      convT: pw(1024) w1w(4096) w2w(4096) -> [N][K] planes
//  [9216,10752)  convN: k1,k2,q1,q2,v1,v2 -> natural planes
//  [10752,11264) cls embed (512 seqs)
//  [11264,11776) bU[jj] = Wk_h[j,:] . bq_h   (2048 dots of len 512)
//  [11776,11780) bvp[c] = [v1b|v2b] @ Wp[:,c] + pb[c]
// ===========================================================================
struct PrepArgs {
    const int* toks; const float* emb; const float* pos;
    const float *pw, *w1w, *w2w;
    const float *k1w, *k2w, *q1w, *q2w, *v1w, *v2w;
    const float *q1b, *q2b, *v1b, *v2b, *pb;
    u16 *WpTHi, *WpTLo, *W1THi, *W1TLo, *W2THi, *W2TLo;
    u16 *WkNHi, *WkNLo, *WqNHi, *WqNLo, *WvNHi, *WvNLo;
    float* XclsF; u16 *XclsHi, *XclsLo;
    float *bU, *bvp;
};

__global__ __launch_bounds__(256)
void prep_kernel(PrepArgs P)
{
    const int id = blockIdx.x, t = threadIdx.x;
    if (id < 9216) {                                    // ---- convT ----
        const float* W; u16 *Hi, *Lo; int K, N, local;
        if (id < 1024)      { W = P.pw;  Hi = P.WpTHi; Lo = P.WpTLo; K = 1024; N = 1024; local = id; }
        else if (id < 5120) { W = P.w1w; Hi = P.W1THi; Lo = P.W1TLo; K = 1024; N = 4096; local = id - 1024; }
        else                { W = P.w2w; Hi = P.W2THi; Lo = P.W2TLo; K = 4096; N = 1024; local = id - 5120; }
        __shared__ float tile[32][33];
        const int tn = N >> 5;
        const int k0 = (local / tn) << 5, n0 = (local % tn) << 5;
        {
            int kk = t >> 3, nn = (t & 7) * 4;
            float4 v = *(const float4*)(W + (size_t)(k0 + kk) * N + n0 + nn);
            tile[kk][nn] = v.x; tile[kk][nn + 1] = v.y;
            tile[kk][nn + 2] = v.z; tile[kk][nn + 3] = v.w;
        }
        __syncthreads();
        {
            int nn = t >> 3, kk = (t & 7) * 4;
            u16x4 h, l;
            #pragma unroll
            for (int j = 0; j < 4; ++j) {
                float f = tile[kk + j][nn];
                u16 hh = f2bf(f);
                h[j] = hh;
                l[j] = f2bf(f - bf2f(hh));
            }
            size_t o = (size_t)(n0 + nn) * K + k0 + kk;
            *(u16x4*)(Hi + o) = h;
            *(u16x4*)(Lo + o) = l;
        }
    } else if (id < 10752) {                            // ---- convN ----
        const int seg = (id - 9216) >> 8, local = (id - 9216) & 255;
        const float* src; u16 *Hi, *Lo;
        const size_t HO = (size_t)1024 * 512;
        switch (seg) {
            case 0: src = P.k1w; Hi = P.WkNHi;      Lo = P.WkNLo;      break;
            case 1: src = P.k2w; Hi = P.WkNHi + HO; Lo = P.WkNLo + HO; break;
            case 2: src = P.q1w; Hi = P.WqNHi;      Lo = P.WqNLo;      break;
            case 3: src = P.q2w; Hi = P.WqNHi + HO; Lo = P.WqNLo + HO; break;
            case 4: src = P.v1w; Hi = P.WvNHi;      Lo = P.WvNLo;      break;
            default:src = P.v2w; Hi = P.WvNHi + HO; Lo = P.WvNLo + HO; break;
        }
        const size_t e = ((size_t)local * 256 + t) * 8;
        const float4* p = (const float4*)(src + e);
        float4 v0 = p[0], v1 = p[1];
        float f[8] = {v0.x, v0.y, v0.z, v0.w, v1.x, v1.y, v1.z, v1.w};
        u16 hv[8], lv[8];
        #pragma unroll
        for (int j = 0; j < 8; ++j) {
            u16 h = f2bf(f[j]);
            hv[j] = h;
            lv[j] = f2bf(f[j] - bf2f(h));
        }
        *(u16x4*)(Hi + e)     = *(u16x4*)&hv[0];
        *(u16x4*)(Hi + e + 4) = *(u16x4*)&hv[4];
        *(u16x4*)(Lo + e)     = *(u16x4*)&lv[0];
        *(u16x4*)(Lo + e + 4) = *(u16x4*)&lv[4];
    } else if (id < 11264) {                            // ---- cls embed ----
        const int n = id - 10752;
        const int tok = P.toks[n * Tn];
        float4 e = ((const float4*)(P.emb + (size_t)tok * Hd))[t];
        float4 p = ((const float4*)P.pos)[t];
        float f[4] = {e.x + p.x, e.y + p.y, e.z + p.z, e.w + p.w};
        ((float4*)(P.XclsF + (size_t)n * Hd))[t] = make_float4(f[0], f[1], f[2], f[3]);
        u16x4 hv, lv;
        #pragma unroll
        for (int j = 0; j < 4; ++j) {
            u16 h = f2bf(f[j]);
            hv[j] = h;
            lv[j] = f2bf(f[j] - bf2f(h));
        }
        *(u16x4*)(P.XclsHi + (size_t)n * Hd + t * 4) = hv;
        *(u16x4*)(P.XclsLo + (size_t)n * Hd + t * 4) = lv;
    } else if (id < 11776) {                            // ---- bU ----
        const int b = id - 11264;
        const int wave = t >> 6, lane = t & 63;
        const int jj = b * 4 + wave;
        const int head = jj >> 10, j = jj & 1023;
        const float* row = (head ? P.k2w : P.k1w) + (size_t)j * 512;
        const float* bqp = head ? P.q2b : P.q1b;
        float4 r0 = ((const float4*)row)[lane * 2];
        float4 r1 = ((const float4*)row)[lane * 2 + 1];
        float4 b0 = ((const float4*)bqp)[lane * 2];
        float4 b1 = ((const float4*)bqp)[lane * 2 + 1];
        float d = r0.x*b0.x + r0.y*b0.y + r0.z*b0.z + r0.w*b0.w
                + r1.x*b1.x + r1.y*b1.y + r1.z*b1.z + r1.w*b1.w;
        #pragma unroll
        for (int off = 32; off; off >>= 1) d += __shfl_xor(d, off);
        if (lane == 0) P.bU[jj] = d;
    } else {                                            // ---- bvp ----
        const int c = (id - 11776) * 256 + t;
        float acc = P.pb[c];
        for (int j = 0; j < 512; ++j) acc += P.v1b[j] * P.pw[(size_t)j * 1024 + c];
        for (int j = 0; j < 512; ++j) acc += P.v2b[j] * P.pw[(size_t)(j + 512) * 1024 + c];
        P.bvp[c] = acc;
    }
}

// ===========================================================================
// device GEMM: C = A@B^T, 3-term bf16 split, 64x128 tile, BK=32, 4 waves.
// Persistent tile loop (t0, tstride). flags: 1=RELU 2=PLANES 4=SPLIT.
// ===========================================================================
__device__ __forceinline__ void gemm_dev(
    const u16* Ahi, const u16* Alo, int lda, size_t az,
    const u16* Bhi, const u16* Blo, int ldb, size_t bz,
    const float* bias, float* C, u16* CHi, u16* CLo, int ldc, int crz, int ccz,
    int M, int N, int K, int nz, int flags,
    float* Cp, size_t pstride, char* lds, int tid, int t0, int tstride)
{
    const bool RELU = flags & 1, PLANES = flags & 2, SPLIT = flags & 4;
    const int ncol = N >> 7;
    const int tpz = (M >> 6) * ncol;
    const int ntiles = nz * tpz;

    const int ra = tid >> 2, ga = tid & 3;
    const int rb = tid >> 1, gb = (tid & 1) << 1;
    const int wA  = ((ra >> 4) << 10) | (ga << 8) | ((((ra & 15) ^ (ga << 1)) & 15) << 4);
    const int wB0 = ((rb >> 4) << 10) | (gb << 8) | ((((rb & 15) ^ (gb << 1)) & 15) << 4);
    const int wB1 = ((rb >> 4) << 10) | ((gb + 1) << 8) | ((((rb & 15) ^ ((gb + 1) << 1)) & 15) << 4);
    const int wv = tid >> 6, lane = tid & 63;
    const int wr = wv >> 1, wc = wv & 1;
    const int l15 = lane & 15, l4 = lane >> 4;
    const int rsw = (l15 ^ (l4 << 1)) << 4;
    int fA[2], fB[4];
    #pragma unroll
    for (int m = 0; m < 2; ++m) fA[m] = (((wr << 1) + m) << 10) | (l4 << 8) | rsw;
    #pragma unroll
    for (int n = 0; n < 4; ++n) fB[n] = (((wc << 2) + n) << 10) | (l4 << 8) | rsw;

    for (int t = t0; t < ntiles; t += tstride) {
        const int z = t / tpz, r = t - z * tpz;
        const int tm = r / ncol;
        const int bm = tm << 6, bn = (r - tm * ncol) << 7;
        int kc = K, kb = 0;
        const u16 *ah = Ahi, *al = Alo, *bh = Bhi, *bl = Blo;
        if (SPLIT) { kc = K / nz; kb = z * kc; }
        else { ah += z * az; al += z * az; bh += z * bz; bl += z * bz; }

        const u16* pAh = ah + (size_t)(bm + ra) * lda + kb + ga * 8;
        const u16* pAl = al + (size_t)(bm + ra) * lda + kb + ga * 8;
        const u16* pBh = bh + (size_t)(bn + rb) * ldb + kb + gb * 8;
        const u16* pBl = bl + (size_t)(bn + rb) * ldb + kb + gb * 8;

        f32x4 acc[2][4] = {};

        uint4 sAh = *(const uint4*)pAh;
        uint4 sAl = *(const uint4*)pAl;
        uint4 sBh0 = *(const uint4*)pBh, sBh1 = *(const uint4*)(pBh + 8);
        uint4 sBl0 = *(const uint4*)pBl, sBl1 = *(const uint4*)(pBl + 8);

        for (int k0 = 0; k0 < kc; k0 += 32) {
            __syncthreads();
            *(uint4*)(lds + wA)          = sAh;
            *(uint4*)(lds + 4096 + wA)   = sAl;
            *(uint4*)(lds + 8192 + wB0)  = sBh0;
            *(uint4*)(lds + 8192 + wB1)  = sBh1;
            *(uint4*)(lds + 16384 + wB0) = sBl0;
            *(uint4*)(lds + 16384 + wB1) = sBl1;
            __syncthreads();
            if (k0 + 32 < kc) {
                pAh += 32; pAl += 32; pBh += 32; pBl += 32;
                sAh = *(const uint4*)pAh;
                sAl = *(const uint4*)pAl;
                sBh0 = *(const uint4*)pBh; sBh1 = *(const uint4*)(pBh + 8);
                sBl0 = *(const uint4*)pBl; sBl1 = *(const uint4*)(pBl + 8);
            }
            bf16x8 a8[2], c8[2], b8[4], d8[4];
            #pragma unroll
            for (int m = 0; m < 2; ++m) {
                a8[m] = *(const bf16x8*)(lds + fA[m]);
                c8[m] = *(const bf16x8*)(lds + 4096 + fA[m]);
            }
            #pragma unroll
            for (int n = 0; n < 4; ++n) {
                b8[n] = *(const bf16x8*)(lds + 8192 + fB[n]);
                d8[n] = *(const bf16x8*)(lds + 16384 + fB[n]);
            }
            #pragma unroll
            for (int m = 0; m < 2; ++m)
                #pragma unroll
                for (int n = 0; n < 4; ++n) {
                    acc[m][n] = __builtin_amdgcn_mfma_f32_16x16x32_bf16(a8[m], b8[n], acc[m][n], 0, 0, 0);
                    acc[m][n] = __builtin_amdgcn_mfma_f32_16x16x32_bf16(c8[m], b8[n], acc[m][n], 0, 0, 0);
                    acc[m][n] = __builtin_amdgcn_mfma_f32_16x16x32_bf16(a8[m], d8[n], acc[m][n], 0, 0, 0);
                }
        }

        #pragma unroll
        for (int n = 0; n < 4; ++n) {
            const int col = bn + (wc << 6) + n * 16 + l15;
            const float bv = (!SPLIT && bias) ? bias[col] : 0.f;
            const int colz = SPLIT ? col : col + z * ccz;
            #pragma unroll
            for (int m = 0; m < 2; ++m) {
                const int row0 = bm + (wr << 5) + m * 16 + l4 * 4;
                #pragma unroll
                for (int rg = 0; rg < 4; ++rg) {
                    const int row = row0 + rg;
                    float v = acc[m][n][rg];
                    if (SPLIT) {
                        Cp[z * pstride + (size_t)row * N + col] = v;
                    } else {
                        const int rowz = row + z * crz;
                        v += bv;
                        if (RELU) v = fmaxf(v, 0.f);
                        if (PLANES) {
                            u16 hh = f2bf(v);
                            CHi[(size_t)rowz * ldc + colz] = hh;
                            CLo[(size_t)rowz * ldc + colz] = f2bf(v - bf2f(hh));
                        } else {
                            C[(size_t)rowz * ldc + colz] = v;
                        }
                    }
                }
            }
        }
    }
}

// ===========================================================================
// cooperative kernel: 8 stages with grid.sync between.
// ===========================================================================
struct CoopArgs {
    const int* toks; const float* emb; const float* pos;
    const float *w1b, *w2b, *lg, *lb, *flw, *flb;
    const u16 *WpTHi, *WpTLo, *W1THi, *W1TLo, *W2THi, *W2TLo;
    const u16 *WkNHi, *WkNLo, *WqNHi, *WqNLo, *WvNHi, *WvNLo;
    const float* XclsF; const u16 *XclsHi, *XclsLo;
    const float *bU, *bvp;
    u16 *BgHi, *BgLo, *WvpHi, *WvpLo;
    float* U; u16 *YHi, *YLo;
    float* Hb; u16 *HbHi, *HbLo;
    u16 *EHi, *ELo;
    float* Cp;
    float* out;
};

__global__ __launch_bounds__(256, 2)
void coop_kernel(CoopArgs A)
{
    cg::grid_group grid = cg::this_grid();
    __shared__ alignas(16) char ldsbuf[24576];
    const int tid = threadIdx.x;
    const int gsz = (int)gridDim.x;
    const size_t HO = (size_t)1024 * 512;
    const size_t PSTR = (size_t)Nb * Hd;

    // ---- S0: Bg = Wk@Wq^T (per head) || Wvp = Wp^T-slices @ Wv ----
    {
        const int half = gsz >> 1;
        if ((int)blockIdx.x < half)
            gemm_dev(A.WkNHi, A.WkNLo, 512, HO, A.WqNHi, A.WqNLo, 512, HO,
                     nullptr, nullptr, A.BgHi, A.BgLo, 1024, 1024, 0,
                     1024, 1024, 512, 2, 2, nullptr, 0, ldsbuf, tid, blockIdx.x, half);
        else
            gemm_dev(A.WpTHi, A.WpTLo, 1024, 512, A.WvNHi, A.WvNLo, 512, HO,
                     nullptr, nullptr, A.WvpHi, A.WvpLo, 2048, 0, 1024,
                     1024, 1024, 512, 2, 2, nullptr, 0, ldsbuf, tid, blockIdx.x - half, half);
    }
    grid.sync();

    // ---- S1: U = Xcls @ Bg^T + bU ----
    gemm_dev(A.XclsHi, A.XclsLo, 1024, 0, A.BgHi, A.BgLo, 1024, 0,
             A.bU, A.U, nullptr, nullptr, 2048, 0, 0,
             512, 2048, 1024, 1, 0, nullptr, 0, ldsbuf, tid, blockIdx.x, gsz);
    grid.sync();

    // ---- S2: attention gather ----
    {
        float* us = (float*)ldsbuf;            // 2048 f
        float* ps = (float*)(ldsbuf + 8192);   // 2 x 64 f
        const int wave = tid >> 6, lane = tid & 63;
        for (int n = blockIdx.x; n < Nb; n += gsz) {
            ((float4*)us)[tid]       = ((const float4*)(A.U + (size_t)n * 2048))[tid];
            ((float4*)us)[tid + 256] = ((const float4*)(A.U + (size_t)n * 2048))[tid + 256];
            __syncthreads();
            const int* tk = A.toks + n * Tn;
            for (int s = wave; s < Tn; s += 4) {
                const int tok = tk[s];
                const float4* er = (const float4*)(A.emb + (size_t)tok * Hd);
                const float4* pr = (const float4*)(A.pos + (size_t)s * Hd);
                float d1 = 0.f, d2 = 0.f;
                #pragma unroll
                for (int i = 0; i < 4; ++i) {
                    const int c = i * 64 + lane;
                    float4 e = er[c], p = pr[c];
                    float x0 = e.x + p.x, x1 = e.y + p.y, x2 = e.z + p.z, x3 = e.w + p.w;
                    const float* u1 = us + c * 4;
                    const float* u2 = us + 1024 + c * 4;
                    d1 += x0*u1[0] + x1*u1[1] + x2*u1[2] + x3*u1[3];
                    d2 += x0*u2[0] + x1*u2[1] + x2*u2[2] + x3*u2[3];
                }
                #pragma unroll
                for (int off = 32; off; off >>= 1) {
                    d1 += __shfl_xor(d1, off);
                    d2 += __shfl_xor(d2, off);
                }
                if (lane == 0) {
                    ps[s]      = d1 * 0.044194173824159216f;
                    ps[64 + s] = d2 * 0.044194173824159216f;
                }
            }
            __syncthreads();
            if (wave < 2) {
                float v = (lane < Tn) ? ps[wave * 64 + lane] : -INFINITY;
                float mx = v;
                #pragma unroll
                for (int off = 32; off; off >>= 1) mx = fmaxf(mx, __shfl_xor(mx, off));
                float e = (lane < Tn) ? __expf(v - mx) : 0.f;
                float sum = e;
                #pragma unroll
                for (int off = 32; off; off >>= 1) sum += __shfl_xor(sum, off);
                if (lane < Tn) ps[wave * 64 + lane] = e / sum;
            }
            __syncthreads();
            float4 a1 = make_float4(0.f, 0.f, 0.f, 0.f);
            float4 a2 = make_float4(0.f, 0.f, 0.f, 0.f);
            for (int s = 0; s < Tn; ++s) {
                const float p1 = ps[s], p2 = ps[64 + s];
                float4 e = ((const float4*)(A.emb + (size_t)tk[s] * Hd))[tid];
                float4 p = ((const float4*)(A.pos + (size_t)s * Hd))[tid];
                float x0 = e.x + p.x, x1 = e.y + p.y, x2 = e.z + p.z, x3 = e.w + p.w;
                a1.x = fmaf(p1, x0, a1.x); a1.y = fmaf(p1, x1, a1.y);
                a1.z = fmaf(p1, x2, a1.z); a1.w = fmaf(p1, x3, a1.w);
                a2.x = fmaf(p2, x0, a2.x); a2.y = fmaf(p2, x1, a2.y);
                a2.z = fmaf(p2, x2, a2.z); a2.w = fmaf(p2, x3, a2.w);
            }
            float f1[4] = {a1.x, a1.y, a1.z, a1.w};
            float f2[4] = {a2.x, a2.y, a2.z, a2.w};
            u16x4 h1, l1, h2, l2;
            #pragma unroll
            for (int j = 0; j < 4; ++j) {
                u16 h = f2bf(f1[j]); h1[j] = h; l1[j] = f2bf(f1[j] - bf2f(h));
                h = f2bf(f2[j]);     h2[j] = h; l2[j] = f2bf(f2[j] - bf2f(h));
            }
            const size_t o = (size_t)n * 2048 + tid * 4;
            *(u16x4*)(A.YHi + o) = h1;          *(u16x4*)(A.YLo + o) = l1;
            *(u16x4*)(A.YHi + o + 1024) = h2;   *(u16x4*)(A.YLo + o + 1024) = l2;
        }
    }
    grid.sync();

    // ---- S3: Hb partials = Y @ Wvp^T (split-K=4) ----
    gemm_dev(A.YHi, A.YLo, 2048, 0, A.WvpHi, A.WvpLo, 2048, 0,
             nullptr, nullptr, nullptr, nullptr, 0, 0, 0,
             512, 1024, 2048, 4, 4, A.Cp, PSTR, ldsbuf, tid, blockIdx.x, gsz);
    grid.sync();

    // ---- S4: Hb = reduce + bvp + Xcls ; LN -> Hb fp32 + planes ----
    {
        float* shr = (float*)ldsbuf;
        const int lane = tid & 63, w = tid >> 6;
        for (int r = blockIdx.x; r < Nb; r += gsz) {
            const size_t base = (size_t)r * Hd;
            float4 v0 = ((const float4*)(A.Cp + base))[tid];
            float4 v1 = ((const float4*)(A.Cp + PSTR + base))[tid];
            float4 v2 = ((const float4*)(A.Cp + 2 * PSTR + base))[tid];
            float4 v3 = ((const float4*)(A.Cp + 3 * PSTR + base))[tid];
            float4 bb = ((const float4*)A.bvp)[tid];
            float4 xc = ((const float4*)(A.XclsF + base))[tid];
            float4 v;
            v.x = v0.x + v1.x + v2.x + v3.x + bb.x + xc.x;
            v.y = v0.y + v1.y + v2.y + v3.y + bb.y + xc.y;
            v.z = v0.z + v1.z + v2.z + v3.z + bb.z + xc.z;
            v.w = v0.w + v1.w + v2.w + v3.w + bb.w + xc.w;
            float s = v.x + v.y + v.z + v.w;
            float q = v.x*v.x + v.y*v.y + v.z*v.z + v.w*v.w;
            #pragma unroll
            for (int off = 32; off; off >>= 1) {
                s += __shfl_xor(s, off);
                q += __shfl_xor(q, off);
            }
            if (lane == 0) { shr[w] = s; shr[4 + w] = q; }
            __syncthreads();
            s = shr[0] + shr[1] + shr[2] + shr[3];
            q = shr[4] + shr[5] + shr[6] + shr[7];
            __syncthreads();
            const float mean = s * (1.f / Hd);
            const float var = q * (1.f / Hd) - mean * mean;
            const float rstd = rsqrtf(var + 1e-5f);
            float4 gv = ((const float4*)A.lg)[tid];
            float4 bv = ((const float4*)A.lb)[tid];
            float f[4];
            f[0] = (v.x - mean) * rstd * gv.x + bv.x;
            f[1] = (v.y - mean) * rstd * gv.y + bv.y;
            f[2] = (v.z - mean) * rstd * gv.z + bv.z;
            f[3] = (v.w - mean) * rstd * gv.w + bv.w;
            ((float4*)(A.Hb + base))[tid] = make_float4(f[0], f[1], f[2], f[3]);
            u16x4 hv, lv;
            #pragma unroll
            for (int j = 0; j < 4; ++j) {
                u16 hh = f2bf(f[j]);
                hv[j] = hh;
                lv[j] = f2bf(f[j] - bf2f(hh));
            }
            *(u16x4*)(A.HbHi + base + tid * 4) = hv;
            *(u16x4*)(A.HbLo + base + tid * 4) = lv;
        }
    }
    grid.sync();

    // ---- S5: E = relu(Hb @ W1 + w1b) -> planes ----
    gemm_dev(A.HbHi, A.HbLo, 1024, 0, A.W1THi, A.W1TLo, 1024, 0,
             A.w1b, nullptr, A.EHi, A.ELo, 4096, 0, 0,
             512, 4096, 1024, 1, 3, nullptr, 0, ldsbuf, tid, blockIdx.x, gsz);
    grid.sync();

    // ---- S6: w2 partials = E @ W2^T (split-K=4) ----
    gemm_dev(A.EHi, A.ELo, 4096, 0, A.W2THi, A.W2TLo, 4096, 0,
             nullptr, nullptr, nullptr, nullptr, 0, 0, 0,
             512, 1024, 4096, 4, 4, A.Cp, PSTR, ldsbuf, tid, blockIdx.x, gsz);
    grid.sync();

    // ---- S7: reduce + w2b + Hb ; LN ; dot flw ; sigmoid ----
    {
        float* shr = (float*)ldsbuf;
        const int lane = tid & 63, w = tid >> 6;
        for (int r = blockIdx.x; r < Nb; r += gsz) {
            const size_t base = (size_t)r * Hd;
            float4 v0 = ((const float4*)(A.Cp + base))[tid];
            float4 v1 = ((const float4*)(A.Cp + PSTR + base))[tid];
            float4 v2 = ((const float4*)(A.Cp + 2 * PSTR + base))[tid];
            float4 v3 = ((const float4*)(A.Cp + 3 * PSTR + base))[tid];
            float4 bb = ((const float4*)A.w2b)[tid];
            float4 hh = ((const float4*)(A.Hb + base))[tid];
            float4 v;
            v.x = v0.x + v1.x + v2.x + v3.x + bb.x + hh.x;
            v.y = v0.y + v1.y + v2.y + v3.y + bb.y + hh.y;
            v.z = v0.z + v1.z + v2.z + v3.z + bb.z + hh.z;
            v.w = v0.w + v1.w + v2.w + v3.w + bb.w + hh.w;
            float s = v.x + v.y + v.z + v.w;
            float q = v.x*v.x + v.y*v.y + v.z*v.z + v.w*v.w;
            #pragma unroll
            for (int off = 32; off; off >>= 1) {
                s += __shfl_xor(s, off);
                q += __shfl_xor(q, off);
            }
            if (lane == 0) { shr[w] = s; shr[4 + w] = q; }
            __syncthreads();
            s = shr[0] + shr[1] + shr[2] + shr[3];
            q = shr[4] + shr[5] + shr[6] + shr[7];
            __syncthreads();
            const float mean = s * (1.f / Hd);
            const float var = q * (1.f / Hd) - mean * mean;
            const float rstd = rsqrtf(var + 1e-5f);
            float4 gv = ((const float4*)A.lg)[tid];
            float4 bv = ((const float4*)A.lb)[tid];
            float4 wv = ((const float4*)A.flw)[tid];
            float d = ((v.x - mean) * rstd * gv.x + bv.x) * wv.x
                    + ((v.y - mean) * rstd * gv.y + bv.y) * wv.y
                    + ((v.z - mean) * rstd * gv.z + bv.z) * wv.z
                    + ((v.w - mean) * rstd * gv.w + bv.w) * wv.w;
            #pragma unroll
            for (int off = 32; off; off >>= 1) d += __shfl_xor(d, off);
            if (lane == 0) shr[8 + w] = d;
            __syncthreads();
            if (tid == 0) {
                float z = shr[8] + shr[9] + shr[10] + shr[11] + A.flb[0];
                A.out[r] = 1.f / (1.f + expf(-z));
            }
            __syncthreads();
        }
    }
}

// ===========================================================================
// host
// ===========================================================================
extern "C" void kernel_launch(void* const* d_in, const int* in_sizes, int n_in,
                              void* d_out, int out_size, void* d_ws, size_t ws_size,
                              hipStream_t stream)
{
    const int*   toks = (const int*)d_in[0];
    const float* emb  = (const float*)d_in[1];
    const float* pos  = (const float*)d_in[2];
    const float* q1w = (const float*)d_in[3];  const float* q1b = (const float*)d_in[4];
    const float* k1w = (const float*)d_in[5];
    const float* v1w = (const float*)d_in[7];  const float* v1b = (const float*)d_in[8];
    const float* q2w = (const float*)d_in[9];  const float* q2b = (const float*)d_in[10];
    const float* k2w = (const float*)d_in[11];
    const float* v2w = (const float*)d_in[13]; const float* v2b = (const float*)d_in[14];
    const float* pw  = (const float*)d_in[15]; const float* pb  = (const float*)d_in[16];
    const float* lg  = (const float*)d_in[17]; const float* lb  = (const float*)d_in[18];
    const float* w1w = (const float*)d_in[19]; const float* w1b = (const float*)d_in[20];
    const float* w2w = (const float*)d_in[21]; const float* w2b = (const float*)d_in[22];
    const float* flw = (const float*)d_in[23]; const float* flb = (const float*)d_in[24];
    float* out = (float*)d_out;
    char* wsb  = (char*)d_ws;

    size_t off = 0;
    auto alloc = [&](size_t bytes) { size_t o = off; off = (off + bytes + 255) & ~(size_t)255; return o; };

    u16* WpTHi = (u16*)(wsb + alloc(1024 * 1024 * 2));
    u16* WpTLo = (u16*)(wsb + alloc(1024 * 1024 * 2));
    u16* W1THi = (u16*)(wsb + alloc(4096 * 1024 * 2));
    u16* W1TLo = (u16*)(wsb + alloc(4096 * 1024 * 2));
    u16* W2THi = (u16*)(wsb + alloc(1024 * 4096 * 2));
    u16* W2TLo = (u16*)(wsb + alloc(1024 * 4096 * 2));
    u16* WkNHi = (u16*)(wsb + alloc(2 * 1024 * 512 * 2));
    u16* WkNLo = (u16*)(wsb + alloc(2 * 1024 * 512 * 2));
    u16* WqNHi = (u16*)(wsb + alloc(2 * 1024 * 512 * 2));
    u16* WqNLo = (u16*)(wsb + alloc(2 * 1024 * 512 * 2));
    u16* WvNHi = (u16*)(wsb + alloc(2 * 1024 * 512 * 2));
    u16* WvNLo = (u16*)(wsb + alloc(2 * 1024 * 512 * 2));
    u16* BgHi  = (u16*)(wsb + alloc(2048 * 1024 * 2));
    u16* BgLo  = (u16*)(wsb + alloc(2048 * 1024 * 2));
    u16* WvpHi = (u16*)(wsb + alloc(1024 * 2048 * 2));
    u16* WvpLo = (u16*)(wsb + alloc(1024 * 2048 * 2));
    float* bU  = (float*)(wsb + alloc(2048 * 4));
    float* bvp = (float*)(wsb + alloc(1024 * 4));
    float* XclsF = (float*)(wsb + alloc((size_t)Nb * Hd * 4));
    u16* XclsHi  = (u16*)(wsb + alloc((size_t)Nb * Hd * 2));
    u16* XclsLo  = (u16*)(wsb + alloc((size_t)Nb * Hd * 2));
    float* U   = (float*)(wsb + alloc((size_t)Nb * 2048 * 4));
    u16* YHi   = (u16*)(wsb + alloc((size_t)Nb * 2048 * 2));
    u16* YLo   = (u16*)(wsb + alloc((size_t)Nb * 2048 * 2));
    float* Hb  = (float*)(wsb + alloc((size_t)Nb * Hd * 4));
    u16* HbHi  = (u16*)(wsb + alloc((size_t)Nb * Hd * 2));
    u16* HbLo  = (u16*)(wsb + alloc((size_t)Nb * Hd * 2));
    u16* EHi   = (u16*)(wsb + alloc((size_t)Nb * 4096 * 2));
    u16* ELo   = (u16*)(wsb + alloc((size_t)Nb * 4096 * 2));
    float* Cp  = (float*)(wsb + alloc((size_t)4 * Nb * Hd * 4));

    PrepArgs P;
    P.toks = toks; P.emb = emb; P.pos = pos;
    P.pw = pw; P.w1w = w1w; P.w2w = w2w;
    P.k1w = k1w; P.k2w = k2w; P.q1w = q1w; P.q2w = q2w; P.v1w = v1w; P.v2w = v2w;
    P.q1b = q1b; P.q2b = q2b; P.v1b = v1b; P.v2b = v2b; P.pb = pb;
    P.WpTHi = WpTHi; P.WpTLo = WpTLo; P.W1THi = W1THi; P.W1TLo = W1TLo;
    P.W2THi = W2THi; P.W2TLo = W2TLo;
    P.WkNHi = WkNHi; P.WkNLo = WkNLo; P.WqNHi = WqNHi; P.WqNLo = WqNLo;
    P.WvNHi = WvNHi; P.WvNLo = WvNLo;
    P.XclsF = XclsF; P.XclsHi = XclsHi; P.XclsLo = XclsLo;
    P.bU = bU; P.bvp = bvp;
    prep_kernel<<<11780, 256, 0, stream>>>(P);

    CoopArgs C;
    C.toks = toks; C.emb = emb; C.pos = pos;
    C.w1b = w1b; C.w2b = w2b; C.lg = lg; C.lb = lb; C.flw = flw; C.flb = flb;
    C.WpTHi = WpTHi; C.WpTLo = WpTLo; C.W1THi = W1THi; C.W1TLo = W1TLo;
    C.W2THi = W2THi; C.W2TLo = W2TLo;
    C.WkNHi = WkNHi; C.WkNLo = WkNLo; C.WqNHi = WqNHi; C.WqNLo = WqNLo;
    C.WvNHi = WvNHi; C.WvNLo = WvNLo;
    C.XclsF = XclsF; C.XclsHi = XclsHi; C.XclsLo = XclsLo;
    C.bU = bU; C.bvp = bvp;
    C.BgHi = BgHi; C.BgLo = BgLo; C.WvpHi = WvpHi; C.WvpLo = WvpLo;
    C.U = U; C.YHi = YHi; C.YLo = YLo;
    C.Hb = Hb; C.HbHi = HbHi; C.HbLo = HbLo;
    C.EHi = EHi; C.ELo = ELo; C.Cp = Cp; C.out = out;

    int maxb = 1;
    (void)hipOccupancyMaxActiveBlocksPerMultiprocessor(&maxb, coop_kernel, 256, 0);
    if (maxb < 1) maxb = 1;
    int grid = maxb * 256;
    if (grid > 512) grid = 512;
    grid &= ~1;
    if (grid < 2) grid = 2;

    void* kargs[1] = { (void*)&C };
    hipLaunchCooperativeKernel(coop_kernel, dim3(grid), dim3(256), kargs, 0, stream);
}

// Round 7
// 175.125 us; speedup vs baseline: 2.7634x; 2.7634x over previous
//
#include <hip/hip_runtime.h>
#include <math.h>

typedef float  f32x4  __attribute__((ext_vector_type(4)));
typedef short  bf16x8 __attribute__((ext_vector_type(8)));
typedef unsigned short u16;
typedef unsigned int   u32;
typedef unsigned short u16x2 __attribute__((ext_vector_type(2)));
typedef unsigned short u16x4 __attribute__((ext_vector_type(4)));
typedef unsigned short u16x8 __attribute__((ext_vector_type(8)));

constexpr int Tn = 43, Hd = 1024, Nb = 512;

__device__ __forceinline__ u16 f2bf(float f) {
    u32 u = __float_as_uint(f);
    u32 r = u + 0x7FFFu + ((u >> 16) & 1u);
    return (u16)(r >> 16);
}
__device__ __forceinline__ float bf2f(u16 h) {
    return __uint_as_float(((u32)h) << 16);
}

// ===========================================================================
// D1 PREP: all weight conversions + CLS embed + bq concat. Segmented grid.
//  [0,10240)      convT: pw | w1w | w2w | q1w | q2w -> [N][K] hi/lo planes
//  [10240,11264)  convN: k1,k2,v1,v2 -> natural hi/lo planes
//  [11264,11776)  cls embed (512 seqs)
//  [11776]        bq = [q1b|q2b]
// ===========================================================================
struct PrepArgs {
    const int* toks; const float* emb; const float* pos;
    const float *pw, *w1w, *w2w, *q1w, *q2w;
    const float *k1w, *k2w, *v1w, *v2w;
    const float *q1b, *q2b;
    u16 *WpTHi, *WpTLo, *W1THi, *W1TLo, *W2THi, *W2TLo, *WqTHi, *WqTLo;
    u16 *WkNHi, *WkNLo, *WvNHi, *WvNLo;
    float* XclsF; u16 *XclsHi, *XclsLo;
    float* bq;
};

__global__ __launch_bounds__(256)
void prep_kernel(PrepArgs P)
{
    const int id = blockIdx.x, t = threadIdx.x;
    if (id < 10240) {                                   // ---- convT ----
        const float* W; u16 *Hi, *Lo; int K, N, local;
        if (id < 1024)      { W = P.pw;  Hi = P.WpTHi; Lo = P.WpTLo; K = 1024; N = 1024; local = id; }
        else if (id < 5120) { W = P.w1w; Hi = P.W1THi; Lo = P.W1TLo; K = 1024; N = 4096; local = id - 1024; }
        else if (id < 9216) { W = P.w2w; Hi = P.W2THi; Lo = P.W2TLo; K = 4096; N = 1024; local = id - 5120; }
        else if (id < 9728) { W = P.q1w; Hi = P.WqTHi; Lo = P.WqTLo; K = 1024; N = 512;  local = id - 9216; }
        else { W = P.q2w; Hi = P.WqTHi + 512 * 1024; Lo = P.WqTLo + 512 * 1024; K = 1024; N = 512; local = id - 9728; }
        __shared__ float tile[32][33];
        const int tn = N >> 5;
        const int k0 = (local / tn) << 5, n0 = (local % tn) << 5;
        {
            int kk = t >> 3, nn = (t & 7) * 4;
            float4 v = *(const float4*)(W + (size_t)(k0 + kk) * N + n0 + nn);
            tile[kk][nn] = v.x; tile[kk][nn + 1] = v.y;
            tile[kk][nn + 2] = v.z; tile[kk][nn + 3] = v.w;
        }
        __syncthreads();
        {
            int nn = t >> 3, kk = (t & 7) * 4;
            u16x4 h, l;
            #pragma unroll
            for (int j = 0; j < 4; ++j) {
                float f = tile[kk + j][nn];
                u16 hh = f2bf(f);
                h[j] = hh;
                l[j] = f2bf(f - bf2f(hh));
            }
            size_t o = (size_t)(n0 + nn) * K + k0 + kk;
            *(u16x4*)(Hi + o) = h;
            *(u16x4*)(Lo + o) = l;
        }
    } else if (id < 11264) {                            // ---- convN ----
        const int seg = (id - 10240) >> 8, local = (id - 10240) & 255;
        const float* src; u16 *Hi, *Lo;
        const size_t HO = (size_t)1024 * 512;
        switch (seg) {
            case 0: src = P.k1w; Hi = P.WkNHi;      Lo = P.WkNLo;      break;
            case 1: src = P.k2w; Hi = P.WkNHi + HO; Lo = P.WkNLo + HO; break;
            case 2: src = P.v1w; Hi = P.WvNHi;      Lo = P.WvNLo;      break;
            default:src = P.v2w; Hi = P.WvNHi + HO; Lo = P.WvNLo + HO; break;
        }
        const size_t e = ((size_t)local * 256 + t) * 8;
        const float4* p = (const float4*)(src + e);
        float4 v0 = p[0], v1 = p[1];
        float f[8] = {v0.x, v0.y, v0.z, v0.w, v1.x, v1.y, v1.z, v1.w};
        u16 hv[8], lv[8];
        #pragma unroll
        for (int j = 0; j < 8; ++j) {
            u16 h = f2bf(f[j]);
            hv[j] = h;
            lv[j] = f2bf(f[j] - bf2f(h));
        }
        *(u16x4*)(Hi + e)     = *(u16x4*)&hv[0];
        *(u16x4*)(Hi + e + 4) = *(u16x4*)&hv[4];
        *(u16x4*)(Lo + e)     = *(u16x4*)&lv[0];
        *(u16x4*)(Lo + e + 4) = *(u16x4*)&lv[4];
    } else if (id < 11776) {                            // ---- cls embed ----
        const int n = id - 11264;
        const int tok = P.toks[n * Tn];
        float4 e = ((const float4*)(P.emb + (size_t)tok * Hd))[t];
        float4 p = ((const float4*)P.pos)[t];
        float f[4] = {e.x + p.x, e.y + p.y, e.z + p.z, e.w + p.w};
        ((float4*)(P.XclsF + (size_t)n * Hd))[t] = make_float4(f[0], f[1], f[2], f[3]);
        u16x4 hv, lv;
        #pragma unroll
        for (int j = 0; j < 4; ++j) {
            u16 h = f2bf(f[j]);
            hv[j] = h;
            lv[j] = f2bf(f[j] - bf2f(h));
        }
        *(u16x4*)(P.XclsHi + (size_t)n * Hd + t * 4) = hv;
        *(u16x4*)(P.XclsLo + (size_t)n * Hd + t * 4) = lv;
    } else {                                            // ---- bq ----
        for (int i = t; i < 1024; i += 256)
            P.bq[i] = (i < 512) ? P.q1b[i] : P.q2b[i - 512];
    }
}

// ===========================================================================
// device GEMM: C = A@B^T, 3-term bf16 split, 64x128 tile, BK=32, 4 waves.
// Persistent tile loop (t0, tstride). flags: 1=RELU 2=PLANES 4=SPLIT.
// ===========================================================================
__device__ __forceinline__ void gemm_dev(
    const u16* Ahi, const u16* Alo, int lda, size_t az,
    const u16* Bhi, const u16* Blo, int ldb, size_t bz,
    const float* bias, float* C, u16* CHi, u16* CLo, int ldc, int crz, int ccz,
    int M, int N, int K, int nz, int flags,
    float* Cp, size_t pstride, char* lds, int tid, int t0, int tstride)
{
    const bool RELU = flags & 1, PLANES = flags & 2, SPLIT = flags & 4;
    const int ncol = N >> 7;
    const int tpz = (M >> 6) * ncol;
    const int ntiles = nz * tpz;

    const int ra = tid >> 2, ga = tid & 3;
    const int rb = tid >> 1, gb = (tid & 1) << 1;
    const int wA  = ((ra >> 4) << 10) | (ga << 8) | ((((ra & 15) ^ (ga << 1)) & 15) << 4);
    const int wB0 = ((rb >> 4) << 10) | (gb << 8) | ((((rb & 15) ^ (gb << 1)) & 15) << 4);
    const int wB1 = ((rb >> 4) << 10) | ((gb + 1) << 8) | ((((rb & 15) ^ ((gb + 1) << 1)) & 15) << 4);
    const int wv = tid >> 6, lane = tid & 63;
    const int wr = wv >> 1, wc = wv & 1;
    const int l15 = lane & 15, l4 = lane >> 4;
    const int rsw = (l15 ^ (l4 << 1)) << 4;
    int fA[2], fB[4];
    #pragma unroll
    for (int m = 0; m < 2; ++m) fA[m] = (((wr << 1) + m) << 10) | (l4 << 8) | rsw;
    #pragma unroll
    for (int n = 0; n < 4; ++n) fB[n] = (((wc << 2) + n) << 10) | (l4 << 8) | rsw;

    for (int t = t0; t < ntiles; t += tstride) {
        const int z = t / tpz, r = t - z * tpz;
        const int tm = r / ncol;
        const int bm = tm << 6, bn = (r - tm * ncol) << 7;
        int kc = K, kb = 0;
        const u16 *ah = Ahi, *al = Alo, *bh = Bhi, *bl = Blo;
        if (SPLIT) { kc = K / nz; kb = z * kc; }
        else { ah += z * az; al += z * az; bh += z * bz; bl += z * bz; }

        const u16* pAh = ah + (size_t)(bm + ra) * lda + kb + ga * 8;
        const u16* pAl = al + (size_t)(bm + ra) * lda + kb + ga * 8;
        const u16* pBh = bh + (size_t)(bn + rb) * ldb + kb + gb * 8;
        const u16* pBl = bl + (size_t)(bn + rb) * ldb + kb + gb * 8;

        f32x4 acc[2][4] = {};

        uint4 sAh = *(const uint4*)pAh;
        uint4 sAl = *(const uint4*)pAl;
        uint4 sBh0 = *(const uint4*)pBh, sBh1 = *(const uint4*)(pBh + 8);
        uint4 sBl0 = *(const uint4*)pBl, sBl1 = *(const uint4*)(pBl + 8);

        for (int k0 = 0; k0 < kc; k0 += 32) {
            __syncthreads();
            *(uint4*)(lds + wA)          = sAh;
            *(uint4*)(lds + 4096 + wA)   = sAl;
            *(uint4*)(lds + 8192 + wB0)  = sBh0;
            *(uint4*)(lds + 8192 + wB1)  = sBh1;
            *(uint4*)(lds + 16384 + wB0) = sBl0;
            *(uint4*)(lds + 16384 + wB1) = sBl1;
            __syncthreads();
            if (k0 + 32 < kc) {
                pAh += 32; pAl += 32; pBh += 32; pBl += 32;
                sAh = *(const uint4*)pAh;
                sAl = *(const uint4*)pAl;
                sBh0 = *(const uint4*)pBh; sBh1 = *(const uint4*)(pBh + 8);
                sBl0 = *(const uint4*)pBl; sBl1 = *(const uint4*)(pBl + 8);
            }
            bf16x8 a8[2], c8[2], b8[4], d8[4];
            #pragma unroll
            for (int m = 0; m < 2; ++m) {
                a8[m] = *(const bf16x8*)(lds + fA[m]);
                c8[m] = *(const bf16x8*)(lds + 4096 + fA[m]);
            }
            #pragma unroll
            for (int n = 0; n < 4; ++n) {
                b8[n] = *(const bf16x8*)(lds + 8192 + fB[n]);
                d8[n] = *(const bf16x8*)(lds + 16384 + fB[n]);
            }
            #pragma unroll
            for (int m = 0; m < 2; ++m)
                #pragma unroll
                for (int n = 0; n < 4; ++n) {
                    acc[m][n] = __builtin_amdgcn_mfma_f32_16x16x32_bf16(a8[m], b8[n], acc[m][n], 0, 0, 0);
                    acc[m][n] = __builtin_amdgcn_mfma_f32_16x16x32_bf16(c8[m], b8[n], acc[m][n], 0, 0, 0);
                    acc[m][n] = __builtin_amdgcn_mfma_f32_16x16x32_bf16(a8[m], d8[n], acc[m][n], 0, 0, 0);
                }
        }

        #pragma unroll
        for (int n = 0; n < 4; ++n) {
            const int col = bn + (wc << 6) + n * 16 + l15;
            const float bv = (!SPLIT && bias) ? bias[col] : 0.f;
            const int colz = SPLIT ? col : col + z * ccz;
            #pragma unroll
            for (int m = 0; m < 2; ++m) {
                const int row0 = bm + (wr << 5) + m * 16 + l4 * 4;
                #pragma unroll
                for (int rg = 0; rg < 4; ++rg) {
                    const int row = row0 + rg;
                    float v = acc[m][n][rg];
                    if (SPLIT) {
                        Cp[z * pstride + (size_t)row * N + col] = v;
                    } else {
                        const int rowz = row + z * crz;
                        v += bv;
                        if (RELU) v = fmaxf(v, 0.f);
                        if (PLANES) {
                            u16 hh = f2bf(v);
                            CHi[(size_t)rowz * ldc + colz] = hh;
                            CLo[(size_t)rowz * ldc + colz] = f2bf(v - bf2f(hh));
                        } else {
                            C[(size_t)rowz * ldc + colz] = v;
                        }
                    }
                }
            }
        }
    }
}

// generic single-GEMM wrapper
struct GArgs {
    const u16 *Ahi, *Alo; int lda; size_t az;
    const u16 *Bhi, *Blo; int ldb; size_t bz;
    const float* bias; float* C; u16 *CHi, *CLo; int ldc, crz, ccz;
    int M, N, K, nz, flags;
    float* Cp; size_t pstride;
};
__global__ __launch_bounds__(256, 2)
void gemm_kernel(GArgs g)
{
    __shared__ alignas(16) char lds[24576];
    gemm_dev(g.Ahi, g.Alo, g.lda, g.az, g.Bhi, g.Blo, g.ldb, g.bz,
             g.bias, g.C, g.CHi, g.CLo, g.ldc, g.crz, g.ccz,
             g.M, g.N, g.K, g.nz, g.flags, g.Cp, g.pstride,
             lds, threadIdx.x, blockIdx.x, gridDim.x);
}

// ===========================================================================
// D2: segmented {Q GEMM | Wvp fold GEMM | bvp fold}
//  [0,64)    Q = Xcls @ WqT^T + bq -> Qpl planes   (M=512,N=1024,K=1024)
//  [64,320)  Wvp[c][h*1024+j] = WpT-slices @ WvN   (z=2,M=1024,N=1024,K=512)
//  [320,576) bvp[c] = [v1b|v2b].WpT[c] + pb[c]     (4 cols/block)
// ===========================================================================
struct D2Args {
    const u16 *XclsHi, *XclsLo, *WqTHi, *WqTLo;
    const u16 *WpTHi, *WpTLo, *WvNHi, *WvNLo;
    const float *bq, *v1b, *v2b, *pb;
    u16 *QplHi, *QplLo, *WvpHi, *WvpLo;
    float* bvp;
};
__global__ __launch_bounds__(256, 2)
void d2_kernel(D2Args A)
{
    __shared__ alignas(16) char lds[24576];
    const int bid = blockIdx.x, tid = threadIdx.x;
    if (bid < 64) {
        gemm_dev(A.XclsHi, A.XclsLo, 1024, 0, A.WqTHi, A.WqTLo, 1024, 0,
                 A.bq, nullptr, A.QplHi, A.QplLo, 1024, 0, 0,
                 512, 1024, 1024, 1, 2, nullptr, 0, lds, tid, bid, 64);
    } else if (bid < 320) {
        gemm_dev(A.WpTHi, A.WpTLo, 1024, 512, A.WvNHi, A.WvNLo, 512, (size_t)1024 * 512,
                 nullptr, nullptr, A.WvpHi, A.WvpLo, 2048, 0, 1024,
                 1024, 1024, 512, 2, 2, nullptr, 0, lds, tid, bid - 64, 256);
    } else {
        const int wave = tid >> 6, lane = tid & 63;
        const int c = (bid - 320) * 4 + wave;
        const int j0 = lane * 16;
        u16x8 h0 = *(const u16x8*)(A.WpTHi + (size_t)c * 1024 + j0);
        u16x8 h1 = *(const u16x8*)(A.WpTHi + (size_t)c * 1024 + j0 + 8);
        u16x8 l0 = *(const u16x8*)(A.WpTLo + (size_t)c * 1024 + j0);
        u16x8 l1 = *(const u16x8*)(A.WpTLo + (size_t)c * 1024 + j0 + 8);
        const float* bsrc = (j0 < 512) ? (A.v1b + j0) : (A.v2b + j0 - 512);
        float d = 0.f;
        #pragma unroll
        for (int j = 0; j < 8; ++j)
            d += bsrc[j] * (bf2f(h0[j]) + bf2f(l0[j]));
        #pragma unroll
        for (int j = 0; j < 8; ++j)
            d += bsrc[8 + j] * (bf2f(h1[j]) + bf2f(l1[j]));
        #pragma unroll
        for (int off = 32; off; off >>= 1) d += __shfl_xor(d, off);
        if (lane == 0) A.bvp[c] = d + A.pb[c];
    }
}

// ===========================================================================
// D4: fused CLS attention from embedding gather (round-5 version).
// scores_sh = x_s . u_h / sqrt(512); y_h = sum_s p_sh x_s -> Y planes [n][2048]
// ===========================================================================
__global__ __launch_bounds__(512)
void attn_direct(const int* __restrict__ toks, const float* __restrict__ emb,
                 const float* __restrict__ pos, const float* __restrict__ U,
                 u16* __restrict__ YHi, u16* __restrict__ YLo)
{
    const int n = blockIdx.x, tid = threadIdx.x;
    __shared__ float us[2048];
    __shared__ float ps[2][48];
    ((float4*)us)[tid] = ((const float4*)(U + (size_t)n * 2048))[tid];
    __syncthreads();

    const int wave = tid >> 6, lane = tid & 63;
    const int* tk = toks + n * Tn;

    for (int s = wave; s < Tn; s += 8) {
        const int tok = tk[s];
        const float4* er = (const float4*)(emb + (size_t)tok * Hd);
        const float4* pr = (const float4*)(pos + (size_t)s * Hd);
        float d1 = 0.f, d2 = 0.f;
        #pragma unroll
        for (int i = 0; i < 4; ++i) {
            const int c = i * 64 + lane;
            float4 e = er[c], p = pr[c];
            float x0 = e.x + p.x, x1 = e.y + p.y, x2 = e.z + p.z, x3 = e.w + p.w;
            const float* u1 = us + c * 4;
            const float* u2 = us + 1024 + c * 4;
            d1 += x0 * u1[0] + x1 * u1[1] + x2 * u1[2] + x3 * u1[3];
            d2 += x0 * u2[0] + x1 * u2[1] + x2 * u2[2] + x3 * u2[3];
        }
        #pragma unroll
        for (int off = 32; off; off >>= 1) {
            d1 += __shfl_xor(d1, off);
            d2 += __shfl_xor(d2, off);
        }
        if (lane == 0) {
            ps[0][s] = d1 * 0.044194173824159216f;
            ps[1][s] = d2 * 0.044194173824159216f;
        }
    }
    __syncthreads();
    if (wave < 2) {
        float v = (lane < Tn) ? ps[wave][lane] : -INFINITY;
        float mx = v;
        #pragma unroll
        for (int off = 32; off; off >>= 1) mx = fmaxf(mx, __shfl_xor(mx, off));
        float e = (lane < Tn) ? __expf(v - mx) : 0.f;
        float sum = e;
        #pragma unroll
        for (int off = 32; off; off >>= 1) sum += __shfl_xor(sum, off);
        if (lane < Tn) ps[wave][lane] = e / sum;
    }
    __syncthreads();

    const int c2 = tid * 2;
    float2 a1 = make_float2(0.f, 0.f), a2 = make_float2(0.f, 0.f);
    float2 e = *(const float2*)(emb + (size_t)tk[0] * Hd + c2);
    float2 p = *(const float2*)(pos + c2);
    for (int s = 0; s < Tn; ++s) {
        float2 en = make_float2(0.f, 0.f), pn = en;
        if (s + 1 < Tn) {
            en = *(const float2*)(emb + (size_t)tk[s + 1] * Hd + c2);
            pn = *(const float2*)(pos + (size_t)(s + 1) * Hd + c2);
        }
        const float p1 = ps[0][s], p2 = ps[1][s];
        const float x0 = e.x + p.x, x1 = e.y + p.y;
        a1.x = fmaf(p1, x0, a1.x); a1.y = fmaf(p1, x1, a1.y);
        a2.x = fmaf(p2, x0, a2.x); a2.y = fmaf(p2, x1, a2.y);
        e = en; p = pn;
    }
    u16x2 h1, l1, h2, l2;
    u16 h;
    h = f2bf(a1.x); h1[0] = h; l1[0] = f2bf(a1.x - bf2f(h));
    h = f2bf(a1.y); h1[1] = h; l1[1] = f2bf(a1.y - bf2f(h));
    h = f2bf(a2.x); h2[0] = h; l2[0] = f2bf(a2.x - bf2f(h));
    h = f2bf(a2.y); h2[1] = h; l2[1] = f2bf(a2.y - bf2f(h));
    const size_t o = (size_t)n * 2048 + c2;
    *(u16x2*)(YHi + o) = h1;          *(u16x2*)(YLo + o) = l1;
    *(u16x2*)(YHi + o + 1024) = h2;   *(u16x2*)(YLo + o + 1024) = l2;
}

// ===========================================================================
// D6: Hb = sum_z Cp[z] + bvp + Xcls ; LN -> Hb fp32 + planes. block per row.
// ===========================================================================
__global__ __launch_bounds__(256)
void reduce_ln(const float* __restrict__ Cp, const float* __restrict__ bvp,
               const float* __restrict__ XclsF, const float* __restrict__ lg,
               const float* __restrict__ lb, float* __restrict__ Hb,
               u16* __restrict__ HbHi, u16* __restrict__ HbLo)
{
    const int tid = threadIdx.x;
    const size_t base = (size_t)blockIdx.x * Hd;
    const size_t P = (size_t)Nb * Hd;
    float4 v0 = ((const float4*)(Cp + base))[tid];
    float4 v1 = ((const float4*)(Cp + P + base))[tid];
    float4 v2 = ((const float4*)(Cp + 2 * P + base))[tid];
    float4 v3 = ((const float4*)(Cp + 3 * P + base))[tid];
    float4 bb = ((const float4*)bvp)[tid];
    float4 xc = ((const float4*)(XclsF + base))[tid];
    float4 v;
    v.x = v0.x + v1.x + v2.x + v3.x + bb.x + xc.x;
    v.y = v0.y + v1.y + v2.y + v3.y + bb.y + xc.y;
    v.z = v0.z + v1.z + v2.z + v3.z + bb.z + xc.z;
    v.w = v0.w + v1.w + v2.w + v3.w + bb.w + xc.w;
    float s = v.x + v.y + v.z + v.w;
    float q = v.x*v.x + v.y*v.y + v.z*v.z + v.w*v.w;
    #pragma unroll
    for (int off = 32; off; off >>= 1) {
        s += __shfl_xor(s, off);
        q += __shfl_xor(q, off);
    }
    __shared__ float ss[4], sq[4];
    const int lane = tid & 63, w = tid >> 6;
    if (lane == 0) { ss[w] = s; sq[w] = q; }
    __syncthreads();
    s = ss[0] + ss[1] + ss[2] + ss[3];
    q = sq[0] + sq[1] + sq[2] + sq[3];
    const float mean = s * (1.f / Hd);
    const float var = q * (1.f / Hd) - mean * mean;
    const float rstd = rsqrtf(var + 1e-5f);
    float4 gv = ((const float4*)lg)[tid];
    float4 bv = ((const float4*)lb)[tid];
    float f[4];
    f[0] = (v.x - mean) * rstd * gv.x + bv.x;
    f[1] = (v.y - mean) * rstd * gv.y + bv.y;
    f[2] = (v.z - mean) * rstd * gv.z + bv.z;
    f[3] = (v.w - mean) * rstd * gv.w + bv.w;
    ((float4*)(Hb + base))[tid] = make_float4(f[0], f[1], f[2], f[3]);
    u16x4 hv, lv;
    #pragma unroll
    for (int j = 0; j < 4; ++j) {
        u16 hh = f2bf(f[j]);
        hv[j] = hh;
        lv[j] = f2bf(f[j] - bf2f(hh));
    }
    *(u16x4*)(HbHi + base + tid * 4) = hv;
    *(u16x4*)(HbLo + base + tid * 4) = lv;
}

// ===========================================================================
// D9: H2 = sum_z Cp[z] + w2b + Hb ; LN ; dot flw ; sigmoid -> out[n]
// ===========================================================================
__global__ __launch_bounds__(256)
void w2ln_final(const float* __restrict__ Cp, const float* __restrict__ w2b,
                const float* __restrict__ Hb, const float* __restrict__ g,
                const float* __restrict__ b, const float* __restrict__ fw,
                const float* __restrict__ fb, float* __restrict__ out)
{
    const int tid = threadIdx.x;
    const size_t base = (size_t)blockIdx.x * Hd;
    const size_t P = (size_t)Nb * Hd;
    float4 v0 = ((const float4*)(Cp + base))[tid];
    float4 v1 = ((const float4*)(Cp + P + base))[tid];
    float4 v2 = ((const float4*)(Cp + 2 * P + base))[tid];
    float4 v3 = ((const float4*)(Cp + 3 * P + base))[tid];
    float4 bb = ((const float4*)w2b)[tid];
    float4 hh = ((const float4*)(Hb + base))[tid];
    float4 v;
    v.x = v0.x + v1.x + v2.x + v3.x + bb.x + hh.x;
    v.y = v0.y + v1.y + v2.y + v3.y + bb.y + hh.y;
    v.z = v0.z + v1.z + v2.z + v3.z + bb.z + hh.z;
    v.w = v0.w + v1.w + v2.w + v3.w + bb.w + hh.w;
    float s = v.x + v.y + v.z + v.w;
    float q = v.x*v.x + v.y*v.y + v.z*v.z + v.w*v.w;
    #pragma unroll
    for (int off = 32; off; off >>= 1) {
        s += __shfl_xor(s, off);
        q += __shfl_xor(q, off);
    }
    __shared__ float ss[4], sq[4], sd[4];
    const int lane = tid & 63, w = tid >> 6;
    if (lane == 0) { ss[w] = s; sq[w] = q; }
    __syncthreads();
    s = ss[0] + ss[1] + ss[2] + ss[3];
    q = sq[0] + sq[1] + sq[2] + sq[3];
    const float mean = s * (1.f / Hd);
    const float var = q * (1.f / Hd) - mean * mean;
    const float rstd = rsqrtf(var + 1e-5f);
    float4 gv = ((const float4*)g)[tid];
    float4 bv = ((const float4*)b)[tid];
    float4 wv = ((const float4*)fw)[tid];
    float d = ((v.x - mean) * rstd * gv.x + bv.x) * wv.x
            + ((v.y - mean) * rstd * gv.y + bv.y) * wv.y
            + ((v.z - mean) * rstd * gv.z + bv.z) * wv.z
            + ((v.w - mean) * rstd * gv.w + bv.w) * wv.w;
    #pragma unroll
    for (int off = 32; off; off >>= 1) d += __shfl_xor(d, off);
    if (lane == 0) sd[w] = d;
    __syncthreads();
    if (tid == 0) {
        float z = sd[0] + sd[1] + sd[2] + sd[3] + fb[0];
        out[blockIdx.x] = 1.f / (1.f + expf(-z));
    }
}

// ===========================================================================
// host
// ===========================================================================
extern "C" void kernel_launch(void* const* d_in, const int* in_sizes, int n_in,
                              void* d_out, int out_size, void* d_ws, size_t ws_size,
                              hipStream_t stream)
{
    const int*   toks = (const int*)d_in[0];
    const float* emb  = (const float*)d_in[1];
    const float* pos  = (const float*)d_in[2];
    const float* q1w = (const float*)d_in[3];  const float* q1b = (const float*)d_in[4];
    const float* k1w = (const float*)d_in[5];
    const float* v1w = (const float*)d_in[7];  const float* v1b = (const float*)d_in[8];
    const float* q2w = (const float*)d_in[9];  const float* q2b = (const float*)d_in[10];
    const float* k2w = (const float*)d_in[11];
    const float* v2w = (const float*)d_in[13]; const float* v2b = (const float*)d_in[14];
    const float* pw  = (const float*)d_in[15]; const float* pb  = (const float*)d_in[16];
    const float* lg  = (const float*)d_in[17]; const float* lb  = (const float*)d_in[18];
    const float* w1w = (const float*)d_in[19]; const float* w1b = (const float*)d_in[20];
    const float* w2w = (const float*)d_in[21]; const float* w2b = (const float*)d_in[22];
    const float* flw = (const float*)d_in[23]; const float* flb = (const float*)d_in[24];
    float* out = (float*)d_out;
    char* wsb  = (char*)d_ws;

    size_t off = 0;
    auto alloc = [&](size_t bytes) { size_t o = off; off = (off + bytes + 255) & ~(size_t)255; return o; };

    u16* WpTHi = (u16*)(wsb + alloc(1024 * 1024 * 2));
    u16* WpTLo = (u16*)(wsb + alloc(1024 * 1024 * 2));
    u16* W1THi = (u16*)(wsb + alloc(4096 * 1024 * 2));
    u16* W1TLo = (u16*)(wsb + alloc(4096 * 1024 * 2));
    u16* W2THi = (u16*)(wsb + alloc(1024 * 4096 * 2));
    u16* W2TLo = (u16*)(wsb + alloc(1024 * 4096 * 2));
    u16* WqTHi = (u16*)(wsb + alloc(1024 * 1024 * 2));
    u16* WqTLo = (u16*)(wsb + alloc(1024 * 1024 * 2));
    u16* WkNHi = (u16*)(wsb + alloc(2 * 1024 * 512 * 2));
    u16* WkNLo = (u16*)(wsb + alloc(2 * 1024 * 512 * 2));
    u16* WvNHi = (u16*)(wsb + alloc(2 * 1024 * 512 * 2));
    u16* WvNLo = (u16*)(wsb + alloc(2 * 1024 * 512 * 2));
    u16* WvpHi = (u16*)(wsb + alloc(1024 * 2048 * 2));
    u16* WvpLo = (u16*)(wsb + alloc(1024 * 2048 * 2));
    float* bq  = (float*)(wsb + alloc(1024 * 4));
    float* bvp = (float*)(wsb + alloc(1024 * 4));
    float* XclsF = (float*)(wsb + alloc((size_t)Nb * Hd * 4));
    u16* XclsHi  = (u16*)(wsb + alloc((size_t)Nb * Hd * 2));
    u16* XclsLo  = (u16*)(wsb + alloc((size_t)Nb * Hd * 2));
    u16* QplHi   = (u16*)(wsb + alloc((size_t)Nb * Hd * 2));
    u16* QplLo   = (u16*)(wsb + alloc((size_t)Nb * Hd * 2));
    float* U   = (float*)(wsb + alloc((size_t)Nb * 2048 * 4));
    u16* YHi   = (u16*)(wsb + alloc((size_t)Nb * 2048 * 2));
    u16* YLo   = (u16*)(wsb + alloc((size_t)Nb * 2048 * 2));
    float* Hb  = (float*)(wsb + alloc((size_t)Nb * Hd * 4));
    u16* HbHi  = (u16*)(wsb + alloc((size_t)Nb * Hd * 2));
    u16* HbLo  = (u16*)(wsb + alloc((size_t)Nb * Hd * 2));
    u16* EHi   = (u16*)(wsb + alloc((size_t)Nb * 4096 * 2));
    u16* ELo   = (u16*)(wsb + alloc((size_t)Nb * 4096 * 2));
    float* Cp  = (float*)(wsb + alloc((size_t)4 * Nb * Hd * 4));

    const size_t HO = (size_t)1024 * 512;
    const size_t PSTR = (size_t)Nb * Hd;

    // ---- D1: prep ----
    PrepArgs P;
    P.toks = toks; P.emb = emb; P.pos = pos;
    P.pw = pw; P.w1w = w1w; P.w2w = w2w; P.q1w = q1w; P.q2w = q2w;
    P.k1w = k1w; P.k2w = k2w; P.v1w = v1w; P.v2w = v2w;
    P.q1b = q1b; P.q2b = q2b;
    P.WpTHi = WpTHi; P.WpTLo = WpTLo; P.W1THi = W1THi; P.W1TLo = W1TLo;
    P.W2THi = W2THi; P.W2TLo = W2TLo; P.WqTHi = WqTHi; P.WqTLo = WqTLo;
    P.WkNHi = WkNHi; P.WkNLo = WkNLo; P.WvNHi = WvNHi; P.WvNLo = WvNLo;
    P.XclsF = XclsF; P.XclsHi = XclsHi; P.XclsLo = XclsLo;
    P.bq = bq;
    prep_kernel<<<11777, 256, 0, stream>>>(P);

    // ---- D2: Q GEMM | Wvp fold | bvp fold ----
    D2Args D;
    D.XclsHi = XclsHi; D.XclsLo = XclsLo; D.WqTHi = WqTHi; D.WqTLo = WqTLo;
    D.WpTHi = WpTHi; D.WpTLo = WpTLo; D.WvNHi = WvNHi; D.WvNLo = WvNLo;
    D.bq = bq; D.v1b = v1b; D.v2b = v2b; D.pb = pb;
    D.QplHi = QplHi; D.QplLo = QplLo; D.WvpHi = WvpHi; D.WvpLo = WvpLo;
    D.bvp = bvp;
    d2_kernel<<<576, 256, 0, stream>>>(D);

    // ---- D3: U_h = Q_h @ Wk_h^T ----
    GArgs gU = { QplHi, QplLo, 1024, 512, WkNHi, WkNLo, 512, HO,
                 nullptr, U, nullptr, nullptr, 2048, 0, 1024,
                 512, 1024, 512, 2, 0, nullptr, 0 };
    gemm_kernel<<<128, 256, 0, stream>>>(gU);

    // ---- D4: attention gather ----
    attn_direct<<<Nb, 512, 0, stream>>>(toks, emb, pos, U, YHi, YLo);

    // ---- D5: Hb partials = Y @ Wvp^T (split-K=4) ----
    GArgs gHb = { YHi, YLo, 2048, 0, WvpHi, WvpLo, 2048, 0,
                  nullptr, nullptr, nullptr, nullptr, 0, 0, 0,
                  512, 1024, 2048, 4, 4, Cp, PSTR };
    gemm_kernel<<<256, 256, 0, stream>>>(gHb);

    // ---- D6: reduce + bvp + Xcls ; LN -> Hb + planes ----
    reduce_ln<<<Nb, 256, 0, stream>>>(Cp, bvp, XclsF, lg, lb, Hb, HbHi, HbLo);

    // ---- D7: E = relu(Hb @ W1 + w1b) -> planes ----
    GArgs gE = { HbHi, HbLo, 1024, 0, W1THi, W1TLo, 1024, 0,
                 w1b, nullptr, EHi, ELo, 4096, 0, 0,
                 512, 4096, 1024, 1, 3, nullptr, 0 };
    gemm_kernel<<<256, 256, 0, stream>>>(gE);

    // ---- D8: w2 partials = E @ W2^T (split-K=4) ----
    GArgs gW2 = { EHi, ELo, 4096, 0, W2THi, W2TLo, 4096, 0,
                  nullptr, nullptr, nullptr, nullptr, 0, 0, 0,
                  512, 1024, 4096, 4, 4, Cp, PSTR };
    gemm_kernel<<<256, 256, 0, stream>>>(gW2);

    // ---- D9: final ----
    w2ln_final<<<Nb, 256, 0, stream>>>(Cp, w2b, Hb, lg, lb, flw, flb, out);
}